// Round 3
// baseline (467.860 us; speedup 1.0000x reference)
//
#include <hip/hip_runtime.h>
#include <stdint.h>

// ---------------------------------------------------------------------------
// MLA forward on MI355X. Round 2: epilogue fusion.
//  G1+G3 fused (bf16 C) -> rmsnorm(wave) -> G2 w/ rope epilogue -> q_b
//  G4 w/ split epilogue -> k_b(nope) + vT(transposed v); prep_krope broadcast
//  attn: exp2-domain softmax, diagonal-only masking. G5 f32+bias.
// ---------------------------------------------------------------------------

typedef short bf16x8 __attribute__((ext_vector_type(8)));
typedef float f32x4  __attribute__((ext_vector_type(4)));
typedef unsigned int u32;

#define RMS_EPS 1.1920929e-07f
// (1/sqrt(192)) * log2(e)
#define SCALE_L2E 0.10411931095f

__device__ __forceinline__ unsigned short f2b(float f) {
  union { float f; uint32_t u; } c; c.f = f;
  uint32_t u = c.u;
  return (unsigned short)((u + 0x7FFFu + ((u >> 16) & 1u)) >> 16);
}
__device__ __forceinline__ float b2f(short s) {
  union { uint32_t u; float f; } c; c.u = ((uint32_t)(unsigned short)s) << 16;
  return c.f;
}
__device__ __forceinline__ void gld16(const short* g, short* l) {
  __builtin_amdgcn_global_load_lds(
      (const __attribute__((address_space(1))) u32*)g,
      (__attribute__((address_space(3))) u32*)l, 16, 0, 0);
}

// ---------------- fp32 -> bf16 conversion ----------------
__global__ void f2bf_kernel(const float* __restrict__ in, short* __restrict__ out, int n4) {
  int i = blockIdx.x * 256 + threadIdx.x;
  if (i >= n4) return;
  float4 v = ((const float4*)in)[i];
  union { ushort4 s; uint2 u; } o;
  o.s.x = f2b(v.x); o.s.y = f2b(v.y); o.s.z = f2b(v.z); o.s.w = f2b(v.w);
  ((uint2*)out)[i] = o.u;
}

__global__ void f2bf_pad_kernel(const float* __restrict__ in, short* __restrict__ out,
                                int n4, int cols4, int src_rows) {
  int i = blockIdx.x * 256 + threadIdx.x;
  if (i >= n4) return;
  int row = i / cols4;
  ushort4 s = {0, 0, 0, 0};
  if (row < src_rows) {
    float4 v = ((const float4*)in)[i];
    s.x = f2b(v.x); s.y = f2b(v.y); s.z = f2b(v.z); s.w = f2b(v.w);
  }
  union { ushort4 ss; uint2 u; } o; o.ss = s;
  ((uint2*)out)[i] = o.u;
}

// ---------------- GEMM: C = A[M,K] @ Bt[N,K]^T with fused epilogues ----------
// 128x128 tile, 4 waves (2x2), global_load_lds 16B staging, 16x16x32 MFMA.
// EPI: 0 = f32 C + bias, 1 = bf16 C, 2 = q rope+scale -> q_b, 3 = kv split.
template <int EPI>
__global__ __launch_bounds__(256) void gemm_bt(
    const short* __restrict__ A, const short* __restrict__ Bt,
    void* __restrict__ Cv, const float* __restrict__ bias,
    int K, int ldc,
    const float* __restrict__ fc, const float* __restrict__ fs,
    short* __restrict__ aux) {
  __shared__ __align__(16) short As[128 * 32];
  __shared__ __align__(16) short Bs[128 * 32];
  int row0 = blockIdx.y * 128, col0 = blockIdx.x * 128;
  int t = threadIdx.x, lane = t & 63, w = t >> 6;
  int wm = w >> 1, wn = w & 1;
  int l15 = lane & 15, l4 = lane >> 4;
  f32x4 acc[4][4] = {};

  int srow = lane >> 2, scol = (lane & 3) * 8;
  const short* Ag = A + (size_t)(row0 + srow) * K + scol;
  const short* Bg = Bt + (size_t)(col0 + srow) * K + scol;

  for (int kt = 0; kt < K; kt += 32) {
#pragma unroll
    for (int c = 0; c < 2; ++c) {
      int blk = w * 2 + c;
      gld16(Ag + (size_t)(blk * 16) * K + kt, As + blk * 512);
      gld16(Bg + (size_t)(blk * 16) * K + kt, Bs + blk * 512);
    }
    __syncthreads();
    bf16x8 af[4], bfr[4];
#pragma unroll
    for (int i = 0; i < 4; ++i) {
      af[i]  = *(const bf16x8*)(As + (wm * 64 + i * 16 + l15) * 32 + l4 * 8);
      bfr[i] = *(const bf16x8*)(Bs + (wn * 64 + i * 16 + l15) * 32 + l4 * 8);
    }
#pragma unroll
    for (int i = 0; i < 4; ++i)
#pragma unroll
      for (int j = 0; j < 4; ++j)
        acc[i][j] = __builtin_amdgcn_mfma_f32_16x16x32_bf16(af[i], bfr[j], acc[i][j], 0, 0, 0);
    __syncthreads();
  }

  if constexpr (EPI == 0) {
    float* C = (float*)Cv;
#pragma unroll
    for (int j = 0; j < 4; ++j) {
      int col = col0 + wn * 64 + j * 16 + l15;
      float bv = bias ? bias[col] : 0.0f;
#pragma unroll
      for (int i = 0; i < 4; ++i) {
        int row = row0 + wm * 64 + i * 16 + l4 * 4;
        float* dst = C + (size_t)row * ldc + col;
#pragma unroll
        for (int r = 0; r < 4; ++r) dst[(size_t)r * ldc] = acc[i][j][r] + bv;
      }
    }
  } else if constexpr (EPI == 1) {
    short* C = (short*)Cv;
#pragma unroll
    for (int j = 0; j < 4; ++j) {
      int col = col0 + wn * 64 + j * 16 + l15;
#pragma unroll
      for (int i = 0; i < 4; ++i) {
        int row = row0 + wm * 64 + i * 16 + l4 * 4;
        short* dst = C + (size_t)row * ldc + col;
#pragma unroll
        for (int r = 0; r < 4; ++r) dst[(size_t)r * ldc] = (short)f2b(acc[i][j][r]);
      }
    }
  } else if constexpr (EPI == 2) {
    // q path: col = h*192 + d; rope d>=128 (pairs in adjacent lanes), scale.
    short* qb = (short*)Cv;
#pragma unroll
    for (int j = 0; j < 4; ++j) {
      int col = col0 + wn * 64 + j * 16 + l15;
      int h = col / 192;
      int d = col - h * 192;
      bool ro = (d >= 128);
      int ir = ro ? ((d - 128) >> 1) : 0;
      bool odd = (l15 & 1);
#pragma unroll
      for (int i = 0; i < 4; ++i) {
        int rowb = row0 + wm * 64 + i * 16 + l4 * 4;
#pragma unroll
        for (int r = 0; r < 4; ++r) {
          int row = rowb + r;
          int b = row >> 11, s = row & 2047;
          float v = acc[i][j][r];
          float pv = __shfl_xor(v, 1);
          float o;
          if (ro) {
            float c = fc[s * 32 + ir], sn = fs[s * 32 + ir];
            o = odd ? (pv * sn + v * c) : (v * c - pv * sn);
          } else {
            o = v;
          }
          qb[((size_t)((b * 16 + h) * 2048 + s)) * 192 + d] = (short)f2b(o * SCALE_L2E);
        }
      }
    }
  } else {  // EPI == 3: kv split. even col-tiles -> k_nope, odd -> vT.
    short* kb = (short*)Cv;
    short* vT = aux;
    int h = col0 >> 8;
    if ((col0 & 128) == 0) {
#pragma unroll
      for (int j = 0; j < 4; ++j) {
        int d = wn * 64 + j * 16 + l15;
#pragma unroll
        for (int i = 0; i < 4; ++i) {
          int rowb = row0 + wm * 64 + i * 16 + l4 * 4;
#pragma unroll
          for (int r = 0; r < 4; ++r) {
            int row = rowb + r;
            int b = row >> 11, s = row & 2047;
            kb[((size_t)((b * 16 + h) * 2048 + s)) * 192 + d] = (short)f2b(acc[i][j][r]);
          }
        }
      }
    } else {
#pragma unroll
      for (int j = 0; j < 4; ++j) {
        int dv = wn * 64 + j * 16 + l15;
#pragma unroll
        for (int i = 0; i < 4; ++i) {
          int s0 = row0 + wm * 64 + i * 16 + l4 * 4;
          int b = s0 >> 11, s = s0 & 2047;
          short4 o;
          o.x = (short)f2b(acc[i][j][0]);
          o.y = (short)f2b(acc[i][j][1]);
          o.z = (short)f2b(acc[i][j][2]);
          o.w = (short)f2b(acc[i][j][3]);
          *(short4*)(vT + ((size_t)((b * 16 + h) * 128 + dv)) * 2048 + s) = o;
        }
      }
    }
  }
}

// ---------------- RMSNorm: one wave per row, bf16 in/out ----------------
template <int W>
__global__ __launch_bounds__(256) void rmsnorm_wave(
    const short* __restrict__ in, const float* __restrict__ wgt,
    short* __restrict__ out, int ld_in) {
  constexpr int NC = W / 512;
  int row = blockIdx.x * 4 + (threadIdx.x >> 6);
  int lane = threadIdx.x & 63;
  const short* x = in + (size_t)row * ld_in + lane * 8;
  float vals[NC * 8];
  float ss = 0.f;
#pragma unroll
  for (int c = 0; c < NC; ++c) {
    bf16x8 v = *(const bf16x8*)(x + c * 512);
#pragma unroll
    for (int k = 0; k < 8; ++k) {
      float f = b2f(v[k]);
      vals[c * 8 + k] = f; ss += f * f;
    }
  }
#pragma unroll
  for (int off = 32; off > 0; off >>= 1) ss += __shfl_xor(ss, off);
  float rs = rsqrtf(ss / (float)W + RMS_EPS);
  short* o = out + (size_t)row * W + lane * 8;
#pragma unroll
  for (int c = 0; c < NC; ++c) {
    const float4* wp = (const float4*)(wgt + c * 512 + lane * 8);
    float4 w0 = wp[0], w1 = wp[1];
    ushort4 lo, hi;
    lo.x = f2b(vals[c * 8 + 0] * rs * w0.x);
    lo.y = f2b(vals[c * 8 + 1] * rs * w0.y);
    lo.z = f2b(vals[c * 8 + 2] * rs * w0.z);
    lo.w = f2b(vals[c * 8 + 3] * rs * w0.w);
    hi.x = f2b(vals[c * 8 + 4] * rs * w1.x);
    hi.y = f2b(vals[c * 8 + 5] * rs * w1.y);
    hi.z = f2b(vals[c * 8 + 6] * rs * w1.z);
    hi.w = f2b(vals[c * 8 + 7] * rs * w1.w);
    *(ushort4*)(o + c * 512) = lo;
    *(ushort4*)(o + c * 512 + 4) = hi;
  }
}

// ---------------- prep_krope: rope shared k_rope, broadcast to 16 heads ------
__global__ void prep_krope_kernel(const short* __restrict__ c1,
                                  const float* __restrict__ fc,
                                  const float* __restrict__ fs,
                                  short* __restrict__ kb) {
  int idx = blockIdx.x * 256 + threadIdx.x;  // B*S*32 = 131072
  int i = idx & 31;
  int s = (idx >> 5) & 2047;
  int b = idx >> 16;
  const short* row = c1 + (size_t)(b * 2048 + s) * 2176 + 1536 + 2 * i;
  float x0 = b2f(row[0]), x1 = b2f(row[1]);
  float c = fc[s * 32 + i], sn = fs[s * 32 + i];
  uint32_t pk = (uint32_t)f2b(x0 * c - x1 * sn) | ((uint32_t)f2b(x0 * sn + x1 * c) << 16);
  size_t base = ((size_t)(b * 16) * 2048 + s) * 192 + 128 + 2 * i;
#pragma unroll
  for (int h = 0; h < 16; ++h)
    *(uint32_t*)(kb + base + (size_t)h * 2048 * 192) = pk;
}

// ---------------- flash attention -------------------------------------------
// grid (16, 32): block does q-tiles {x, 31-x}. 4 waves x 16 q-rows, KT=64.
// exp2-domain softmax (log2e folded into q); mask only the diagonal tile.
__global__ __launch_bounds__(256) void attn_kernel(
    const short* __restrict__ qb, const short* __restrict__ kb,
    const short* __restrict__ vtb, short* __restrict__ ob) {
  __shared__ __align__(16) short Ks[64 * 200];
  __shared__ __align__(16) short Vs[128 * 72];
  __shared__ __align__(16) short Ps[4][16 * 72];
  int bh = blockIdx.y;
  int b = bh >> 4, h = bh & 15;
  int t = threadIdx.x, lane = t & 63, w = t >> 6;
  int l15 = lane & 15, l4 = lane >> 4;
  const short* Kbh = kb + (size_t)bh * 2048 * 192;
  const short* Vbh = vtb + (size_t)bh * 128 * 2048;

  for (int half = 0; half < 2; ++half) {
    int qt = half ? (31 - (int)blockIdx.x) : (int)blockIdx.x;
    int q0 = qt * 64;
    const short* Qbase = qb + ((size_t)bh * 2048 + q0 + w * 16) * 192;
    bf16x8 qf[6];
#pragma unroll
    for (int kk = 0; kk < 6; ++kk)
      qf[kk] = *(const bf16x8*)(Qbase + (size_t)l15 * 192 + kk * 32 + l4 * 8);
    f32x4 oacc[8] = {};
    float m_i[4] = {-1e30f, -1e30f, -1e30f, -1e30f};
    float l_i[4] = {0.f, 0.f, 0.f, 0.f};
    int kend = q0 + 64;

    for (int kt = 0; kt < kend; kt += 64) {
#pragma unroll
      for (int c = 0; c < 6; ++c) {
        int idx = t + 256 * c;
        int r = idx / 24, ch = idx - r * 24;
        *(bf16x8*)(Ks + r * 200 + ch * 8) =
            *(const bf16x8*)(Kbh + (size_t)(kt + r) * 192 + ch * 8);
      }
#pragma unroll
      for (int c = 0; c < 4; ++c) {
        int idx = t + 256 * c;
        int d = idx >> 3, cc = (idx & 7) * 8;
        *(bf16x8*)(Vs + d * 72 + cc) =
            *(const bf16x8*)(Vbh + (size_t)d * 2048 + kt + cc);
      }
      __syncthreads();

      f32x4 s[4] = {};
#pragma unroll
      for (int kk = 0; kk < 6; ++kk) {
#pragma unroll
        for (int c = 0; c < 4; ++c) {
          bf16x8 kf = *(const bf16x8*)(Ks + (c * 16 + l15) * 200 + kk * 32 + l4 * 8);
          s[c] = __builtin_amdgcn_mfma_f32_16x16x32_bf16(qf[kk], kf, s[c], 0, 0, 0);
        }
      }
      bool diag = (kt == q0);
      int qrow = q0 + w * 16 + l4 * 4;
#pragma unroll
      for (int r = 0; r < 4; ++r) {
        float sv[4];
#pragma unroll
        for (int c = 0; c < 4; ++c) {
          sv[c] = s[c][r];
          if (diag) {
            int col = kt + c * 16 + l15;
            if (col > qrow + r) sv[c] = -1e30f;
          }
        }
        float tm = fmaxf(fmaxf(sv[0], sv[1]), fmaxf(sv[2], sv[3]));
#pragma unroll
        for (int off = 1; off < 16; off <<= 1) tm = fmaxf(tm, __shfl_xor(tm, off));
        float newm = fmaxf(m_i[r], tm);
        float alpha = exp2f(m_i[r] - newm);
        float rs = 0.f;
#pragma unroll
        for (int c = 0; c < 4; ++c) {
          float p = exp2f(sv[c] - newm);
          sv[c] = p; rs += p;
        }
#pragma unroll
        for (int off = 1; off < 16; off <<= 1) rs += __shfl_xor(rs, off);
        l_i[r] = l_i[r] * alpha + rs;
        m_i[r] = newm;
#pragma unroll
        for (int dt = 0; dt < 8; ++dt) oacc[dt][r] *= alpha;
        short* prow = &Ps[w][(l4 * 4 + r) * 72];
#pragma unroll
        for (int c = 0; c < 4; ++c) prow[c * 16 + l15] = (short)f2b(sv[c]);
      }
      bf16x8 pf0 = *(const bf16x8*)(&Ps[w][l15 * 72 + l4 * 8]);
      bf16x8 pf1 = *(const bf16x8*)(&Ps[w][l15 * 72 + 32 + l4 * 8]);
#pragma unroll
      for (int dt = 0; dt < 8; ++dt) {
        bf16x8 vf0 = *(const bf16x8*)(Vs + (dt * 16 + l15) * 72 + l4 * 8);
        bf16x8 vf1 = *(const bf16x8*)(Vs + (dt * 16 + l15) * 72 + 32 + l4 * 8);
        oacc[dt] = __builtin_amdgcn_mfma_f32_16x16x32_bf16(pf0, vf0, oacc[dt], 0, 0, 0);
        oacc[dt] = __builtin_amdgcn_mfma_f32_16x16x32_bf16(pf1, vf1, oacc[dt], 0, 0, 0);
      }
      __syncthreads();
    }
#pragma unroll
    for (int r = 0; r < 4; ++r) {
      float inv = 1.0f / l_i[r];
      int row = q0 + w * 16 + l4 * 4 + r;
      short* dst = ob + ((size_t)(b * 2048 + row)) * 2048 + h * 128;
#pragma unroll
      for (int dt = 0; dt < 8; ++dt)
        dst[dt * 16 + l15] = (short)f2b(oacc[dt][r] * inv);
    }
  }
}

// ---------------------------------------------------------------------------
extern "C" void kernel_launch(void* const* d_in, const int* in_sizes, int n_in,
                              void* d_out, int out_size, void* d_ws, size_t ws_size,
                              hipStream_t stream) {
  const float* x    = (const float*)d_in[0];
  const float* fcos = (const float*)d_in[1];
  const float* fsin = (const float*)d_in[2];
  const float* Wqd  = (const float*)d_in[3];
  const float* qnw  = (const float*)d_in[4];
  const float* Wqu  = (const float*)d_in[5];
  const float* Wkvd = (const float*)d_in[6];
  const float* kvnw = (const float*)d_in[7];
  const float* Wkvu = (const float*)d_in[8];
  const float* Wo   = (const float*)d_in[9];
  const float* bo   = (const float*)d_in[10];
  float* out = (float*)d_out;
  char* ws = (char*)d_ws;

  short* x_bf  = (short*)(ws + 0);           // 4096x2048 bf16
  short* w_cat = (short*)(ws + 16777216);    // 2176x2048 (Wqd;Wkvd pad)
  short* w_qu  = (short*)(ws + 25690112);    // 3072x1536
  short* w_kvu = (short*)(ws + 35127296);    // 4096x512
  short* w_o   = (short*)(ws + 39321600);    // 2048x2048
  short* c1    = (short*)(ws + 47710208);    // 4096x2176 bf16 (qdown|krope|ckv)
  short* qn    = (short*)(ws + 65536000);    // 4096x1536 bf16
  short* ckvn  = (short*)(ws + 78118912);    // 4096x512 bf16
  short* q_b   = (short*)(ws + 82313216);    // (B,H,S,192) bf16
  short* k_b   = (short*)(ws + 107479040);   // (B,H,S,192) bf16
  short* vT    = (short*)(ws + 132644864);   // (B,H,128,S) bf16
  short* o_bf  = (short*)(ws + 149422080);   // (B,S,2048) bf16

  // conversions
  f2bf_kernel<<<8192, 256, 0, stream>>>(x, x_bf, 2097152);
  f2bf_kernel<<<3072, 256, 0, stream>>>(Wqd, w_cat, 786432);
  f2bf_pad_kernel<<<1280, 256, 0, stream>>>(Wkvd, w_cat + 1536 * 2048, 327680, 512, 576);
  f2bf_kernel<<<4608, 256, 0, stream>>>(Wqu, w_qu, 1179648);
  f2bf_kernel<<<2048, 256, 0, stream>>>(Wkvu, w_kvu, 524288);
  f2bf_kernel<<<4096, 256, 0, stream>>>(Wo, w_o, 1048576);

  // fused down-projections: c1 = x @ [Wqd;Wkvd]^T  (bf16, ldc 2176)
  gemm_bt<1><<<dim3(17, 32), 256, 0, stream>>>(x_bf, w_cat, c1, nullptr, 2048, 2176,
                                               nullptr, nullptr, nullptr);
  prep_krope_kernel<<<512, 256, 0, stream>>>(c1, fcos, fsin, k_b);
  rmsnorm_wave<1536><<<1024, 256, 0, stream>>>(c1, qnw, qn, 2176);
  rmsnorm_wave<512><<<1024, 256, 0, stream>>>(c1 + 1600, kvnw, ckvn, 2176);

  // up-projections with fused attention-layout epilogues
  gemm_bt<2><<<dim3(24, 32), 256, 0, stream>>>(qn, w_qu, q_b, nullptr, 1536, 0,
                                               fcos, fsin, nullptr);
  gemm_bt<3><<<dim3(32, 32), 256, 0, stream>>>(ckvn, w_kvu, k_b, nullptr, 512, 0,
                                               nullptr, nullptr, vT);

  attn_kernel<<<dim3(16, 32), 256, 0, stream>>>(q_b, k_b, vT, o_bf);

  gemm_bt<0><<<dim3(16, 32), 256, 0, stream>>>(o_bf, w_o, out, bo, 2048, 2048,
                                               nullptr, nullptr, nullptr);
}

// Round 4
// 380.901 us; speedup vs baseline: 1.2283x; 1.2283x over previous
//
#include <hip/hip_runtime.h>
#include <stdint.h>

// ---------------------------------------------------------------------------
// MLA forward on MI355X. Round 3 -> 4:
//  - attn: native exp2 builtin (round-3 exp2f regression fix), XCD-aware
//    block remap (same-bh blocks share one XCD L2), setprio around MFMA.
//  - rest unchanged from round 2/3 fused pipeline.
// ---------------------------------------------------------------------------

typedef short bf16x8 __attribute__((ext_vector_type(8)));
typedef float f32x4  __attribute__((ext_vector_type(4)));
typedef unsigned int u32;

#define RMS_EPS 1.1920929e-07f
// (1/sqrt(192)) * log2(e)
#define SCALE_L2E 0.10411931095f

__device__ __forceinline__ unsigned short f2b(float f) {
  union { float f; uint32_t u; } c; c.f = f;
  uint32_t u = c.u;
  return (unsigned short)((u + 0x7FFFu + ((u >> 16) & 1u)) >> 16);
}
__device__ __forceinline__ float b2f(short s) {
  union { uint32_t u; float f; } c; c.u = ((uint32_t)(unsigned short)s) << 16;
  return c.f;
}
__device__ __forceinline__ void gld16(const short* g, short* l) {
  __builtin_amdgcn_global_load_lds(
      (const __attribute__((address_space(1))) u32*)g,
      (__attribute__((address_space(3))) u32*)l, 16, 0, 0);
}

// ---------------- fp32 -> bf16 conversion ----------------
__global__ void f2bf_kernel(const float* __restrict__ in, short* __restrict__ out, int n4) {
  int i = blockIdx.x * 256 + threadIdx.x;
  if (i >= n4) return;
  float4 v = ((const float4*)in)[i];
  union { ushort4 s; uint2 u; } o;
  o.s.x = f2b(v.x); o.s.y = f2b(v.y); o.s.z = f2b(v.z); o.s.w = f2b(v.w);
  ((uint2*)out)[i] = o.u;
}

__global__ void f2bf_pad_kernel(const float* __restrict__ in, short* __restrict__ out,
                                int n4, int cols4, int src_rows) {
  int i = blockIdx.x * 256 + threadIdx.x;
  if (i >= n4) return;
  int row = i / cols4;
  ushort4 s = {0, 0, 0, 0};
  if (row < src_rows) {
    float4 v = ((const float4*)in)[i];
    s.x = f2b(v.x); s.y = f2b(v.y); s.z = f2b(v.z); s.w = f2b(v.w);
  }
  union { ushort4 ss; uint2 u; } o; o.ss = s;
  ((uint2*)out)[i] = o.u;
}

// ---------------- GEMM: C = A[M,K] @ Bt[N,K]^T with fused epilogues ----------
// EPI: 0 = f32 C + bias, 1 = bf16 C, 2 = q rope+scale -> q_b, 3 = kv split.
template <int EPI>
__global__ __launch_bounds__(256) void gemm_bt(
    const short* __restrict__ A, const short* __restrict__ Bt,
    void* __restrict__ Cv, const float* __restrict__ bias,
    int K, int ldc,
    const float* __restrict__ fc, const float* __restrict__ fs,
    short* __restrict__ aux) {
  __shared__ __align__(16) short As[128 * 32];
  __shared__ __align__(16) short Bs[128 * 32];
  int row0 = blockIdx.y * 128, col0 = blockIdx.x * 128;
  int t = threadIdx.x, lane = t & 63, w = t >> 6;
  int wm = w >> 1, wn = w & 1;
  int l15 = lane & 15, l4 = lane >> 4;
  f32x4 acc[4][4] = {};

  int srow = lane >> 2, scol = (lane & 3) * 8;
  const short* Ag = A + (size_t)(row0 + srow) * K + scol;
  const short* Bg = Bt + (size_t)(col0 + srow) * K + scol;

  for (int kt = 0; kt < K; kt += 32) {
#pragma unroll
    for (int c = 0; c < 2; ++c) {
      int blk = w * 2 + c;
      gld16(Ag + (size_t)(blk * 16) * K + kt, As + blk * 512);
      gld16(Bg + (size_t)(blk * 16) * K + kt, Bs + blk * 512);
    }
    __syncthreads();
    bf16x8 af[4], bfr[4];
#pragma unroll
    for (int i = 0; i < 4; ++i) {
      af[i]  = *(const bf16x8*)(As + (wm * 64 + i * 16 + l15) * 32 + l4 * 8);
      bfr[i] = *(const bf16x8*)(Bs + (wn * 64 + i * 16 + l15) * 32 + l4 * 8);
    }
#pragma unroll
    for (int i = 0; i < 4; ++i)
#pragma unroll
      for (int j = 0; j < 4; ++j)
        acc[i][j] = __builtin_amdgcn_mfma_f32_16x16x32_bf16(af[i], bfr[j], acc[i][j], 0, 0, 0);
    __syncthreads();
  }

  if constexpr (EPI == 0) {
    float* C = (float*)Cv;
#pragma unroll
    for (int j = 0; j < 4; ++j) {
      int col = col0 + wn * 64 + j * 16 + l15;
      float bv = bias ? bias[col] : 0.0f;
#pragma unroll
      for (int i = 0; i < 4; ++i) {
        int row = row0 + wm * 64 + i * 16 + l4 * 4;
        float* dst = C + (size_t)row * ldc + col;
#pragma unroll
        for (int r = 0; r < 4; ++r) dst[(size_t)r * ldc] = acc[i][j][r] + bv;
      }
    }
  } else if constexpr (EPI == 1) {
    short* C = (short*)Cv;
#pragma unroll
    for (int j = 0; j < 4; ++j) {
      int col = col0 + wn * 64 + j * 16 + l15;
#pragma unroll
      for (int i = 0; i < 4; ++i) {
        int row = row0 + wm * 64 + i * 16 + l4 * 4;
        short* dst = C + (size_t)row * ldc + col;
#pragma unroll
        for (int r = 0; r < 4; ++r) dst[(size_t)r * ldc] = (short)f2b(acc[i][j][r]);
      }
    }
  } else if constexpr (EPI == 2) {
    short* qb = (short*)Cv;
#pragma unroll
    for (int j = 0; j < 4; ++j) {
      int col = col0 + wn * 64 + j * 16 + l15;
      int h = col / 192;
      int d = col - h * 192;
      bool ro = (d >= 128);
      int ir = ro ? ((d - 128) >> 1) : 0;
      bool odd = (l15 & 1);
#pragma unroll
      for (int i = 0; i < 4; ++i) {
        int rowb = row0 + wm * 64 + i * 16 + l4 * 4;
#pragma unroll
        for (int r = 0; r < 4; ++r) {
          int row = rowb + r;
          int b = row >> 11, s = row & 2047;
          float v = acc[i][j][r];
          float pv = __shfl_xor(v, 1);
          float o;
          if (ro) {
            float c = fc[s * 32 + ir], sn = fs[s * 32 + ir];
            o = odd ? (pv * sn + v * c) : (v * c - pv * sn);
          } else {
            o = v;
          }
          qb[((size_t)((b * 16 + h) * 2048 + s)) * 192 + d] = (short)f2b(o * SCALE_L2E);
        }
      }
    }
  } else {  // EPI == 3: kv split. even col-tiles -> k_nope, odd -> vT.
    short* kb = (short*)Cv;
    short* vT = aux;
    int h = col0 >> 8;
    if ((col0 & 128) == 0) {
#pragma unroll
      for (int j = 0; j < 4; ++j) {
        int d = wn * 64 + j * 16 + l15;
#pragma unroll
        for (int i = 0; i < 4; ++i) {
          int rowb = row0 + wm * 64 + i * 16 + l4 * 4;
#pragma unroll
          for (int r = 0; r < 4; ++r) {
            int row = rowb + r;
            int b = row >> 11, s = row & 2047;
            kb[((size_t)((b * 16 + h) * 2048 + s)) * 192 + d] = (short)f2b(acc[i][j][r]);
          }
        }
      }
    } else {
#pragma unroll
      for (int j = 0; j < 4; ++j) {
        int dv = wn * 64 + j * 16 + l15;
#pragma unroll
        for (int i = 0; i < 4; ++i) {
          int s0 = row0 + wm * 64 + i * 16 + l4 * 4;
          int b = s0 >> 11, s = s0 & 2047;
          short4 o;
          o.x = (short)f2b(acc[i][j][0]);
          o.y = (short)f2b(acc[i][j][1]);
          o.z = (short)f2b(acc[i][j][2]);
          o.w = (short)f2b(acc[i][j][3]);
          *(short4*)(vT + ((size_t)((b * 16 + h) * 128 + dv)) * 2048 + s) = o;
        }
      }
    }
  }
}

// ---------------- RMSNorm: one wave per row, bf16 in/out ----------------
template <int W>
__global__ __launch_bounds__(256) void rmsnorm_wave(
    const short* __restrict__ in, const float* __restrict__ wgt,
    short* __restrict__ out, int ld_in) {
  constexpr int NC = W / 512;
  int row = blockIdx.x * 4 + (threadIdx.x >> 6);
  int lane = threadIdx.x & 63;
  const short* x = in + (size_t)row * ld_in + lane * 8;
  float vals[NC * 8];
  float ss = 0.f;
#pragma unroll
  for (int c = 0; c < NC; ++c) {
    bf16x8 v = *(const bf16x8*)(x + c * 512);
#pragma unroll
    for (int k = 0; k < 8; ++k) {
      float f = b2f(v[k]);
      vals[c * 8 + k] = f; ss += f * f;
    }
  }
#pragma unroll
  for (int off = 32; off > 0; off >>= 1) ss += __shfl_xor(ss, off);
  float rs = rsqrtf(ss / (float)W + RMS_EPS);
  short* o = out + (size_t)row * W + lane * 8;
#pragma unroll
  for (int c = 0; c < NC; ++c) {
    const float4* wp = (const float4*)(wgt + c * 512 + lane * 8);
    float4 w0 = wp[0], w1 = wp[1];
    ushort4 lo, hi;
    lo.x = f2b(vals[c * 8 + 0] * rs * w0.x);
    lo.y = f2b(vals[c * 8 + 1] * rs * w0.y);
    lo.z = f2b(vals[c * 8 + 2] * rs * w0.z);
    lo.w = f2b(vals[c * 8 + 3] * rs * w0.w);
    hi.x = f2b(vals[c * 8 + 4] * rs * w1.x);
    hi.y = f2b(vals[c * 8 + 5] * rs * w1.y);
    hi.z = f2b(vals[c * 8 + 6] * rs * w1.z);
    hi.w = f2b(vals[c * 8 + 7] * rs * w1.w);
    *(ushort4*)(o + c * 512) = lo;
    *(ushort4*)(o + c * 512 + 4) = hi;
  }
}

// ---------------- prep_krope ----------------
__global__ void prep_krope_kernel(const short* __restrict__ c1,
                                  const float* __restrict__ fc,
                                  const float* __restrict__ fs,
                                  short* __restrict__ kb) {
  int idx = blockIdx.x * 256 + threadIdx.x;  // B*S*32 = 131072
  int i = idx & 31;
  int s = (idx >> 5) & 2047;
  int b = idx >> 16;
  const short* row = c1 + (size_t)(b * 2048 + s) * 2176 + 1536 + 2 * i;
  float x0 = b2f(row[0]), x1 = b2f(row[1]);
  float c = fc[s * 32 + i], sn = fs[s * 32 + i];
  uint32_t pk = (uint32_t)f2b(x0 * c - x1 * sn) | ((uint32_t)f2b(x0 * sn + x1 * c) << 16);
  size_t base = ((size_t)(b * 16) * 2048 + s) * 192 + 128 + 2 * i;
#pragma unroll
  for (int h = 0; h < 16; ++h)
    *(uint32_t*)(kb + base + (size_t)h * 2048 * 192) = pk;
}

// ---------------- flash attention -------------------------------------------
// grid 512 linear; XCD-aware remap: all 16 q-blocks of a bh land on one XCD.
// 4 waves x 16 q-rows, KT=64, exp2-domain softmax via native v_exp_f32.
__global__ __launch_bounds__(256) void attn_kernel(
    const short* __restrict__ qb, const short* __restrict__ kb,
    const short* __restrict__ vtb, short* __restrict__ ob) {
  __shared__ __align__(16) short Ks[64 * 200];
  __shared__ __align__(16) short Vs[128 * 72];
  __shared__ __align__(16) short Ps[4][16 * 72];
  int bid = blockIdx.x;
  int xcd = bid & 7, kk2 = bid >> 3;       // kk2: 0..63
  int bh = xcd * 4 + (kk2 >> 4);           // 4 bh per XCD
  int qx = kk2 & 15;
  int b = bh >> 4, h = bh & 15;
  int t = threadIdx.x, lane = t & 63, w = t >> 6;
  int l15 = lane & 15, l4 = lane >> 4;
  const short* Kbh = kb + (size_t)bh * 2048 * 192;
  const short* Vbh = vtb + (size_t)bh * 128 * 2048;

  for (int half = 0; half < 2; ++half) {
    int qt = half ? (31 - qx) : qx;
    int q0 = qt * 64;
    const short* Qbase = qb + ((size_t)bh * 2048 + q0 + w * 16) * 192;
    bf16x8 qf[6];
#pragma unroll
    for (int kk = 0; kk < 6; ++kk)
      qf[kk] = *(const bf16x8*)(Qbase + (size_t)l15 * 192 + kk * 32 + l4 * 8);
    f32x4 oacc[8] = {};
    float m_i[4] = {-1e30f, -1e30f, -1e30f, -1e30f};
    float l_i[4] = {0.f, 0.f, 0.f, 0.f};
    int kend = q0 + 64;

    for (int kt = 0; kt < kend; kt += 64) {
#pragma unroll
      for (int c = 0; c < 6; ++c) {
        int idx = t + 256 * c;
        int r = idx / 24, ch = idx - r * 24;
        *(bf16x8*)(Ks + r * 200 + ch * 8) =
            *(const bf16x8*)(Kbh + (size_t)(kt + r) * 192 + ch * 8);
      }
#pragma unroll
      for (int c = 0; c < 4; ++c) {
        int idx = t + 256 * c;
        int d = idx >> 3, cc = (idx & 7) * 8;
        *(bf16x8*)(Vs + d * 72 + cc) =
            *(const bf16x8*)(Vbh + (size_t)d * 2048 + kt + cc);
      }
      __syncthreads();

      f32x4 s[4] = {};
      __builtin_amdgcn_s_setprio(1);
#pragma unroll
      for (int kk = 0; kk < 6; ++kk) {
#pragma unroll
        for (int c = 0; c < 4; ++c) {
          bf16x8 kf = *(const bf16x8*)(Ks + (c * 16 + l15) * 200 + kk * 32 + l4 * 8);
          s[c] = __builtin_amdgcn_mfma_f32_16x16x32_bf16(qf[kk], kf, s[c], 0, 0, 0);
        }
      }
      __builtin_amdgcn_s_setprio(0);
      bool diag = (kt == q0);
      int qrow = q0 + w * 16 + l4 * 4;
#pragma unroll
      for (int r = 0; r < 4; ++r) {
        float sv[4];
#pragma unroll
        for (int c = 0; c < 4; ++c) {
          sv[c] = s[c][r];
          if (diag) {
            int col = kt + c * 16 + l15;
            if (col > qrow + r) sv[c] = -1e30f;
          }
        }
        float tm = fmaxf(fmaxf(sv[0], sv[1]), fmaxf(sv[2], sv[3]));
#pragma unroll
        for (int off = 1; off < 16; off <<= 1) tm = fmaxf(tm, __shfl_xor(tm, off));
        float newm = fmaxf(m_i[r], tm);
        float alpha = __builtin_amdgcn_exp2f(m_i[r] - newm);
        float rs = 0.f;
#pragma unroll
        for (int c = 0; c < 4; ++c) {
          float p = __builtin_amdgcn_exp2f(sv[c] - newm);
          sv[c] = p; rs += p;
        }
#pragma unroll
        for (int off = 1; off < 16; off <<= 1) rs += __shfl_xor(rs, off);
        l_i[r] = l_i[r] * alpha + rs;
        m_i[r] = newm;
#pragma unroll
        for (int dt = 0; dt < 8; ++dt) oacc[dt][r] *= alpha;
        short* prow = &Ps[w][(l4 * 4 + r) * 72];
#pragma unroll
        for (int c = 0; c < 4; ++c) prow[c * 16 + l15] = (short)f2b(sv[c]);
      }
      bf16x8 pf0 = *(const bf16x8*)(&Ps[w][l15 * 72 + l4 * 8]);
      bf16x8 pf1 = *(const bf16x8*)(&Ps[w][l15 * 72 + 32 + l4 * 8]);
      __builtin_amdgcn_s_setprio(1);
#pragma unroll
      for (int dt = 0; dt < 8; ++dt) {
        bf16x8 vf0 = *(const bf16x8*)(Vs + (dt * 16 + l15) * 72 + l4 * 8);
        bf16x8 vf1 = *(const bf16x8*)(Vs + (dt * 16 + l15) * 72 + 32 + l4 * 8);
        oacc[dt] = __builtin_amdgcn_mfma_f32_16x16x32_bf16(pf0, vf0, oacc[dt], 0, 0, 0);
        oacc[dt] = __builtin_amdgcn_mfma_f32_16x16x32_bf16(pf1, vf1, oacc[dt], 0, 0, 0);
      }
      __builtin_amdgcn_s_setprio(0);
      __syncthreads();
    }
#pragma unroll
    for (int r = 0; r < 4; ++r) {
      float inv = 1.0f / l_i[r];
      int row = q0 + w * 16 + l4 * 4 + r;
      short* dst = ob + ((size_t)(b * 2048 + row)) * 2048 + h * 128;
#pragma unroll
      for (int dt = 0; dt < 8; ++dt)
        dst[dt * 16 + l15] = (short)f2b(oacc[dt][r] * inv);
    }
  }
}

// ---------------------------------------------------------------------------
extern "C" void kernel_launch(void* const* d_in, const int* in_sizes, int n_in,
                              void* d_out, int out_size, void* d_ws, size_t ws_size,
                              hipStream_t stream) {
  const float* x    = (const float*)d_in[0];
  const float* fcos = (const float*)d_in[1];
  const float* fsin = (const float*)d_in[2];
  const float* Wqd  = (const float*)d_in[3];
  const float* qnw  = (const float*)d_in[4];
  const float* Wqu  = (const float*)d_in[5];
  const float* Wkvd = (const float*)d_in[6];
  const float* kvnw = (const float*)d_in[7];
  const float* Wkvu = (const float*)d_in[8];
  const float* Wo   = (const float*)d_in[9];
  const float* bo   = (const float*)d_in[10];
  float* out = (float*)d_out;
  char* ws = (char*)d_ws;

  short* x_bf  = (short*)(ws + 0);           // 4096x2048 bf16
  short* w_cat = (short*)(ws + 16777216);    // 2176x2048 (Wqd;Wkvd pad)
  short* w_qu  = (short*)(ws + 25690112);    // 3072x1536
  short* w_kvu = (short*)(ws + 35127296);    // 4096x512
  short* w_o   = (short*)(ws + 39321600);    // 2048x2048
  short* c1    = (short*)(ws + 47710208);    // 4096x2176 bf16 (qdown|krope|ckv)
  short* qn    = (short*)(ws + 65536000);    // 4096x1536 bf16
  short* ckvn  = (short*)(ws + 78118912);    // 4096x512 bf16
  short* q_b   = (short*)(ws + 82313216);    // (B,H,S,192) bf16
  short* k_b   = (short*)(ws + 107479040);   // (B,H,S,192) bf16
  short* vT    = (short*)(ws + 132644864);   // (B,H,128,S) bf16
  short* o_bf  = (short*)(ws + 149422080);   // (B,S,2048) bf16

  f2bf_kernel<<<8192, 256, 0, stream>>>(x, x_bf, 2097152);
  f2bf_kernel<<<3072, 256, 0, stream>>>(Wqd, w_cat, 786432);
  f2bf_pad_kernel<<<1280, 256, 0, stream>>>(Wkvd, w_cat + 1536 * 2048, 327680, 512, 576);
  f2bf_kernel<<<4608, 256, 0, stream>>>(Wqu, w_qu, 1179648);
  f2bf_kernel<<<2048, 256, 0, stream>>>(Wkvu, w_kvu, 524288);
  f2bf_kernel<<<4096, 256, 0, stream>>>(Wo, w_o, 1048576);

  gemm_bt<1><<<dim3(17, 32), 256, 0, stream>>>(x_bf, w_cat, c1, nullptr, 2048, 2176,
                                               nullptr, nullptr, nullptr);
  prep_krope_kernel<<<512, 256, 0, stream>>>(c1, fcos, fsin, k_b);
  rmsnorm_wave<1536><<<1024, 256, 0, stream>>>(c1, qnw, qn, 2176);
  rmsnorm_wave<512><<<1024, 256, 0, stream>>>(c1 + 1600, kvnw, ckvn, 2176);

  gemm_bt<2><<<dim3(24, 32), 256, 0, stream>>>(qn, w_qu, q_b, nullptr, 1536, 0,
                                               fcos, fsin, nullptr);
  gemm_bt<3><<<dim3(32, 32), 256, 0, stream>>>(ckvn, w_kvu, k_b, nullptr, 512, 0,
                                               nullptr, nullptr, vT);

  attn_kernel<<<512, 256, 0, stream>>>(q_b, k_b, vT, o_bf);

  gemm_bt<0><<<dim3(16, 32), 256, 0, stream>>>(o_bf, w_o, out, bo, 2048, 2048,
                                               nullptr, nullptr, nullptr);
}